// Round 5
// baseline (214.725 us; speedup 1.0000x reference)
//
#include <hip/hip_runtime.h>

// NGP multiresolution hash-grid interpolation encoding.
// B=262144 points, DIM=3, L=16 levels, T=19 (2^19 entries/level), F=2.
//
// R5: spatial counting-sort of points (32^3 buckets) so waves are spatially
// coherent -> corner loads at low/mid levels merge into few L2 lines
// (model: each random 8B gather occupies a full 128B L2 line slot;
// 33.5M x 128B = 4.3GB at ~37 TB/s L2 ~= the measured 105us floor).
// Kept from R3: level-specialized gather blocks + XCD pinning
// (level = blockIdx&7 -> XCD, two temporal phases), level-major ws,
// LDS transpose. New: transpose scatters each point's 32-float row to
// out[point_id] as one full 128B line (8 lanes x 16B contiguous).

#define NB 262144
#define NL 16
#define TSIZE (1u << 19)
#define TMASK ((1u << 19) - 1u)
#define P1 2654435761u
#define P2 805459861u
#define NBKT 32768  // 32^3 spatial buckets

typedef float vf2 __attribute__((ext_vector_type(2)));
typedef float vf4 __attribute__((ext_vector_type(4)));

__constant__ float RES_C[NL] = {16.f, 20.f, 25.f, 32.f, 40.f, 50.f, 64.f, 80.f,
                                101.f, 128.f, 161.f, 203.f, 256.f, 322.f, 406.f, 512.f};

__device__ __forceinline__ int bucket_of(float px, float py, float pz) {
  int bx = min(31, (int)(px * 32.0f));
  int by = min(31, (int)(py * 32.0f));
  int bz = min(31, (int)(pz * 32.0f));
  return bx | (by << 5) | (bz << 10);
}

__device__ __forceinline__ void ngp_point_level(
    float px, float py, float pz, int l, const float* __restrict__ tables,
    float& o0, float& o1) {
  const float res = RES_C[l];
  const float sx = px * res, sy = py * res, sz = pz * res;
  const float fx = floorf(sx), fy = floorf(sy), fz = floorf(sz);
  const unsigned ix = (unsigned)fx, iy = (unsigned)fy, iz = (unsigned)fz;

  const unsigned hx0 = ix, hx1 = ix + 1u;
  const unsigned hy0 = iy * P1, hy1 = hy0 + P1;
  const unsigned hz0 = iz * P2, hz1 = hz0 + P2;

  const float wx0 = 1.0f - fabsf(sx - fx);
  const float wx1 = 1.0f - fabsf(sx - (fx + 1.0f));
  const float wy0 = 1.0f - fabsf(sy - fy);
  const float wy1 = 1.0f - fabsf(sy - (fy + 1.0f));
  const float wz0 = 1.0f - fabsf(sz - fz);
  const float wz1 = 1.0f - fabsf(sz - (fz + 1.0f));

  const vf2* __restrict__ tbl = (const vf2*)tables + (size_t)l * TSIZE;

  unsigned idxs[8];
#pragma unroll
  for (int v = 0; v < 8; ++v) {
    const unsigned hx = (v & 1) ? hx1 : hx0;
    const unsigned hy = (v & 2) ? hy1 : hy0;
    const unsigned hz = (v & 4) ? hz1 : hz0;
    idxs[v] = (hx ^ hy ^ hz) & TMASK;
  }
  vf2 g[8];
#pragma unroll
  for (int v = 0; v < 8; ++v) g[v] = tbl[idxs[v]];

  o0 = 0.0f; o1 = 0.0f;
#pragma unroll
  for (int v = 0; v < 8; ++v) {
    const float w = ((v & 1) ? wx1 : wx0) * ((v & 2) ? wy1 : wy0) * ((v & 4) ? wz1 : wz0);
    o0 = fmaf(w, g[v].x, o0);
    o1 = fmaf(w, g[v].y, o1);
  }
}

// ---- sort phase ----
__global__ __launch_bounds__(256) void zero_kernel(unsigned* __restrict__ hist) {
  hist[blockIdx.x * 256 + threadIdx.x] = 0u;
}

__global__ __launch_bounds__(256) void hist_kernel(
    const float* __restrict__ x, unsigned* __restrict__ hist) {
  const int b = blockIdx.x * 256 + threadIdx.x;
  const float px = x[b * 3 + 0], py = x[b * 3 + 1], pz = x[b * 3 + 2];
  atomicAdd(&hist[bucket_of(px, py, pz)], 1u);
}

__global__ __launch_bounds__(1024) void scan_kernel(
    const unsigned* __restrict__ hist, unsigned* __restrict__ offs) {
  __shared__ unsigned part[1024];
  const int t = threadIdx.x;
  const int base = t * 32;
  unsigned loc[32];
  unsigned s = 0;
#pragma unroll
  for (int i = 0; i < 32; ++i) { loc[i] = s; s += hist[base + i]; }
  part[t] = s;
  __syncthreads();
  for (int d = 1; d < 1024; d <<= 1) {
    unsigned v = (t >= d) ? part[t - d] : 0u;
    __syncthreads();
    part[t] += v;
    __syncthreads();
  }
  const unsigned pre = (t == 0) ? 0u : part[t - 1];
#pragma unroll
  for (int i = 0; i < 32; ++i) offs[base + i] = pre + loc[i];
}

__global__ __launch_bounds__(256) void scatter_kernel(
    const float* __restrict__ x, unsigned* __restrict__ offs,
    vf4* __restrict__ xp) {
  const int b = blockIdx.x * 256 + threadIdx.x;
  const float px = x[b * 3 + 0], py = x[b * 3 + 1], pz = x[b * 3 + 2];
  const unsigned pos = atomicAdd(&offs[bucket_of(px, py, pz)], 1u);
  vf4 v; v.x = px; v.y = py; v.z = pz; v.w = __uint_as_float((unsigned)b);
  xp[pos] = v;
}

// ---- phase 1: level-specialized gather over sorted points ----
__global__ __launch_bounds__(256) void ngp_gather_sorted_kernel(
    const vf4* __restrict__ xp,        // (B,) sorted: x,y,z,orig_id
    const float* __restrict__ tables,  // (L, 2^19, 2)
    vf2* __restrict__ ws) {            // (L, B) in sorted order
  const int i = blockIdx.x;                    // 0..16383
  const int lvl = (i & 7) | ((i >> 13) << 3);  // XCD pinning + 2 temporal phases
  const int chunk = (i >> 3) & 1023;
  const int p = chunk * 256 + threadIdx.x;

  const vf4 v = __builtin_nontemporal_load(xp + p);

  float o0, o1;
  ngp_point_level(v.x, v.y, v.z, lvl, tables, o0, o1);

  vf2 r; r.x = o0; r.y = o1;
  __builtin_nontemporal_store(r, ws + (size_t)lvl * NB + p);
}

// ---- phase 2: transpose + un-permute. Each point's out row = one 128B line. ----
__global__ __launch_bounds__(256) void ngp_transpose_sorted_kernel(
    const vf2* __restrict__ ws,   // (L, B) sorted order
    const vf4* __restrict__ xp,   // for orig_id in .w
    vf4* __restrict__ out4) {     // (B, 8) float4 rows, original order
  __shared__ vf2 tile[NL][257];
  __shared__ unsigned pid[256];
  const int t = threadIdx.x;
  const int p0 = blockIdx.x * 256;

#pragma unroll
  for (int l = 0; l < NL; ++l) {
    tile[l][t] = __builtin_nontemporal_load(ws + (size_t)l * NB + p0 + t);
  }
  pid[t] = __float_as_uint(xp[p0 + t].w);
  __syncthreads();

#pragma unroll
  for (int k = 0; k < 8; ++k) {
    const int q = k * 256 + t;
    const int pq = q >> 3;  // point slot in this block (8 consecutive lanes share)
    const int wq = q & 7;   // float4 index within the 128B row
    const vf2 a = tile[2 * wq + 0][pq];
    const vf2 c = tile[2 * wq + 1][pq];
    vf4 v; v.x = a.x; v.y = a.y; v.z = c.x; v.w = c.y;
    out4[(size_t)pid[pq] * 8 + wq] = v;
  }
}

// ---- R3 path (no sort) if ws is small ----
__global__ __launch_bounds__(256) void ngp_gather_kernel(
    const float* __restrict__ x, const float* __restrict__ tables,
    vf2* __restrict__ ws) {
  const int i = blockIdx.x;
  const int lvl = (i & 7) | ((i >> 13) << 3);
  const int chunk = (i >> 3) & 1023;
  const int b = chunk * 256 + threadIdx.x;
  const float px = __builtin_nontemporal_load(x + b * 3 + 0);
  const float py = __builtin_nontemporal_load(x + b * 3 + 1);
  const float pz = __builtin_nontemporal_load(x + b * 3 + 2);
  float o0, o1;
  ngp_point_level(px, py, pz, lvl, tables, o0, o1);
  vf2 r; r.x = o0; r.y = o1;
  __builtin_nontemporal_store(r, ws + (size_t)lvl * NB + b);
}

__global__ __launch_bounds__(256) void ngp_transpose_kernel(
    const vf2* __restrict__ ws, vf4* __restrict__ out4) {
  __shared__ vf2 tile[NL][257];
  const int t = threadIdx.x;
  const int p0 = blockIdx.x * 256;
#pragma unroll
  for (int l = 0; l < NL; ++l) {
    tile[l][t] = __builtin_nontemporal_load(ws + (size_t)l * NB + p0 + t);
  }
  __syncthreads();
#pragma unroll
  for (int k = 0; k < 8; ++k) {
    const int q = k * 256 + t;
    const int pq = q >> 3;
    const int wq = q & 7;
    const vf2 a = tile[2 * wq + 0][pq];
    const vf2 c = tile[2 * wq + 1][pq];
    vf4 v; v.x = a.x; v.y = a.y; v.z = c.x; v.w = c.y;
    __builtin_nontemporal_store(v, out4 + (size_t)p0 * 8 + q);
  }
}

// ---- last-resort fused fallback ----
__global__ __launch_bounds__(256) void ngp_fused_kernel(
    const float* __restrict__ x, const float* __restrict__ tables,
    float* __restrict__ out) {
  const int tid = blockIdx.x * blockDim.x + threadIdx.x;
  const int l = tid & (NL - 1);
  const int b = tid >> 4;
  float o0, o1;
  ngp_point_level(x[b * 3], x[b * 3 + 1], x[b * 3 + 2], l, tables, o0, o1);
  float2 r = make_float2(o0, o1);
  ((float2*)out)[tid] = r;
}

extern "C" void kernel_launch(void* const* d_in, const int* in_sizes, int n_in,
                              void* d_out, int out_size, void* d_ws, size_t ws_size,
                              hipStream_t stream) {
  const float* x = (const float*)d_in[0];
  const float* tables = (const float*)d_in[1];
  float* out = (float*)d_out;

  const size_t ws2_b = (size_t)NL * NB * sizeof(vf2);   // 32 MB
  const size_t xp_b = (size_t)NB * sizeof(vf4);         // 4 MB
  const size_t hist_b = (size_t)NBKT * sizeof(unsigned);  // 128 KB
  const size_t sorted_need = ws2_b + xp_b + 2 * hist_b;

  if (ws_size >= sorted_need) {
    char* base = (char*)d_ws;
    vf2* ws2 = (vf2*)base;
    vf4* xp = (vf4*)(base + ws2_b);
    unsigned* hist = (unsigned*)(base + ws2_b + xp_b);
    unsigned* offs = (unsigned*)(base + ws2_b + xp_b + hist_b);

    zero_kernel<<<NBKT / 256, 256, 0, stream>>>(hist);
    hist_kernel<<<NB / 256, 256, 0, stream>>>(x, hist);
    scan_kernel<<<1, 1024, 0, stream>>>(hist, offs);
    scatter_kernel<<<NB / 256, 256, 0, stream>>>(x, offs, xp);
    ngp_gather_sorted_kernel<<<NB * NL / 256, 256, 0, stream>>>(xp, tables, ws2);
    ngp_transpose_sorted_kernel<<<NB / 256, 256, 0, stream>>>(ws2, xp, (vf4*)out);
  } else if (ws_size >= ws2_b) {
    vf2* ws = (vf2*)d_ws;
    ngp_gather_kernel<<<NB * NL / 256, 256, 0, stream>>>(x, tables, ws);
    ngp_transpose_kernel<<<NB / 256, 256, 0, stream>>>(ws, (vf4*)out);
  } else {
    ngp_fused_kernel<<<NB * NL / 256, 256, 0, stream>>>(x, tables, out);
  }
}

// Round 6
// 204.717 us; speedup vs baseline: 1.0489x; 1.0489x over previous
//
#include <hip/hip_runtime.h>

// NGP multiresolution hash-grid interpolation encoding.
// B=262144 points, DIM=3, L=16 levels, T=19 (2^19 entries/level), F=2.
//
// R6: level-phased REPLICATED residency (single change vs R5).
// R5 post-mortem: pinning level->XCD serves each expensive level from ONE
// XCD's L2 (~16 req/cyc -> ~55us/level); cheap-level XCDs idle. Tables are
// read-only, so instead dispatch level-major: all 8 XCDs work on the same
// level, table replicated in every L2 (4 MiB each). Dispatch window ~2
// levels (2048 resident blocks), so interleave cheap/expensive levels
// {0,15,1,14,...} -> window = 1 expensive (L2) + 1 cheap (L1, thanks to the
// spatial sort) -> no 8 MiB thrash. Sort (32^3 counting sort) kept from R5.

#define NB 262144
#define NL 16
#define TSIZE (1u << 19)
#define TMASK ((1u << 19) - 1u)
#define P1 2654435761u
#define P2 805459861u
#define NBKT 32768  // 32^3 spatial buckets

typedef float vf2 __attribute__((ext_vector_type(2)));
typedef float vf4 __attribute__((ext_vector_type(4)));

__constant__ float RES_C[NL] = {16.f, 20.f, 25.f, 32.f, 40.f, 50.f, 64.f, 80.f,
                                101.f, 128.f, 161.f, 203.f, 256.f, 322.f, 406.f, 512.f};

// cheap/expensive interleave: adjacent dispatch windows hold one small-
// working-set level and one full-4MiB level.
__constant__ int SEQ_C[NL] = {0, 15, 1, 14, 2, 13, 3, 12, 4, 11, 5, 10, 6, 9, 7, 8};

__device__ __forceinline__ int bucket_of(float px, float py, float pz) {
  int bx = min(31, (int)(px * 32.0f));
  int by = min(31, (int)(py * 32.0f));
  int bz = min(31, (int)(pz * 32.0f));
  return bx | (by << 5) | (bz << 10);
}

__device__ __forceinline__ void ngp_point_level(
    float px, float py, float pz, int l, const float* __restrict__ tables,
    float& o0, float& o1) {
  const float res = RES_C[l];
  const float sx = px * res, sy = py * res, sz = pz * res;
  const float fx = floorf(sx), fy = floorf(sy), fz = floorf(sz);
  const unsigned ix = (unsigned)fx, iy = (unsigned)fy, iz = (unsigned)fz;

  const unsigned hx0 = ix, hx1 = ix + 1u;
  const unsigned hy0 = iy * P1, hy1 = hy0 + P1;
  const unsigned hz0 = iz * P2, hz1 = hz0 + P2;

  const float wx0 = 1.0f - fabsf(sx - fx);
  const float wx1 = 1.0f - fabsf(sx - (fx + 1.0f));
  const float wy0 = 1.0f - fabsf(sy - fy);
  const float wy1 = 1.0f - fabsf(sy - (fy + 1.0f));
  const float wz0 = 1.0f - fabsf(sz - fz);
  const float wz1 = 1.0f - fabsf(sz - (fz + 1.0f));

  const vf2* __restrict__ tbl = (const vf2*)tables + (size_t)l * TSIZE;

  unsigned idxs[8];
#pragma unroll
  for (int v = 0; v < 8; ++v) {
    const unsigned hx = (v & 1) ? hx1 : hx0;
    const unsigned hy = (v & 2) ? hy1 : hy0;
    const unsigned hz = (v & 4) ? hz1 : hz0;
    idxs[v] = (hx ^ hy ^ hz) & TMASK;
  }
  vf2 g[8];
#pragma unroll
  for (int v = 0; v < 8; ++v) g[v] = tbl[idxs[v]];

  o0 = 0.0f; o1 = 0.0f;
#pragma unroll
  for (int v = 0; v < 8; ++v) {
    const float w = ((v & 1) ? wx1 : wx0) * ((v & 2) ? wy1 : wy0) * ((v & 4) ? wz1 : wz0);
    o0 = fmaf(w, g[v].x, o0);
    o1 = fmaf(w, g[v].y, o1);
  }
}

// ---- sort phase ----
__global__ __launch_bounds__(256) void zero_kernel(unsigned* __restrict__ hist) {
  hist[blockIdx.x * 256 + threadIdx.x] = 0u;
}

__global__ __launch_bounds__(256) void hist_kernel(
    const float* __restrict__ x, unsigned* __restrict__ hist) {
  const int b = blockIdx.x * 256 + threadIdx.x;
  const float px = x[b * 3 + 0], py = x[b * 3 + 1], pz = x[b * 3 + 2];
  atomicAdd(&hist[bucket_of(px, py, pz)], 1u);
}

__global__ __launch_bounds__(1024) void scan_kernel(
    const unsigned* __restrict__ hist, unsigned* __restrict__ offs) {
  __shared__ unsigned part[1024];
  const int t = threadIdx.x;
  const int base = t * 32;
  unsigned loc[32];
  unsigned s = 0;
#pragma unroll
  for (int i = 0; i < 32; ++i) { loc[i] = s; s += hist[base + i]; }
  part[t] = s;
  __syncthreads();
  for (int d = 1; d < 1024; d <<= 1) {
    unsigned v = (t >= d) ? part[t - d] : 0u;
    __syncthreads();
    part[t] += v;
    __syncthreads();
  }
  const unsigned pre = (t == 0) ? 0u : part[t - 1];
#pragma unroll
  for (int i = 0; i < 32; ++i) offs[base + i] = pre + loc[i];
}

__global__ __launch_bounds__(256) void scatter_kernel(
    const float* __restrict__ x, unsigned* __restrict__ offs,
    vf4* __restrict__ xp) {
  const int b = blockIdx.x * 256 + threadIdx.x;
  const float px = x[b * 3 + 0], py = x[b * 3 + 1], pz = x[b * 3 + 2];
  const unsigned pos = atomicAdd(&offs[bucket_of(px, py, pz)], 1u);
  vf4 v; v.x = px; v.y = py; v.z = pz; v.w = __uint_as_float((unsigned)b);
  xp[pos] = v;
}

// ---- phase 1: level-phased gather over sorted points ----
__global__ __launch_bounds__(256) void ngp_gather_sorted_kernel(
    const vf4* __restrict__ xp,        // (B,) sorted: x,y,z,orig_id
    const float* __restrict__ tables,  // (L, 2^19, 2)
    vf2* __restrict__ ws) {            // (L, B) in sorted order
  const int i = blockIdx.x;        // 0..16383
  const int lvl = SEQ_C[i >> 10];  // level-major phases, cheap/expensive interleave
  const int chunk = i & 1023;
  const int p = chunk * 256 + threadIdx.x;

  const vf4 v = __builtin_nontemporal_load(xp + p);

  float o0, o1;
  ngp_point_level(v.x, v.y, v.z, lvl, tables, o0, o1);

  vf2 r; r.x = o0; r.y = o1;
  __builtin_nontemporal_store(r, ws + (size_t)lvl * NB + p);
}

// ---- phase 2: transpose + un-permute. Each point's out row = one 128B line. ----
__global__ __launch_bounds__(256) void ngp_transpose_sorted_kernel(
    const vf2* __restrict__ ws,   // (L, B) sorted order
    const vf4* __restrict__ xp,   // for orig_id in .w
    vf4* __restrict__ out4) {     // (B, 8) float4 rows, original order
  __shared__ vf2 tile[NL][257];
  __shared__ unsigned pid[256];
  const int t = threadIdx.x;
  const int p0 = blockIdx.x * 256;

#pragma unroll
  for (int l = 0; l < NL; ++l) {
    tile[l][t] = __builtin_nontemporal_load(ws + (size_t)l * NB + p0 + t);
  }
  pid[t] = __float_as_uint(xp[p0 + t].w);
  __syncthreads();

#pragma unroll
  for (int k = 0; k < 8; ++k) {
    const int q = k * 256 + t;
    const int pq = q >> 3;  // point slot in this block (8 consecutive lanes share)
    const int wq = q & 7;   // float4 index within the 128B row
    const vf2 a = tile[2 * wq + 0][pq];
    const vf2 c = tile[2 * wq + 1][pq];
    vf4 v; v.x = a.x; v.y = a.y; v.z = c.x; v.w = c.y;
    out4[(size_t)pid[pq] * 8 + wq] = v;
  }
}

// ---- R3 path (no sort) if ws is small ----
__global__ __launch_bounds__(256) void ngp_gather_kernel(
    const float* __restrict__ x, const float* __restrict__ tables,
    vf2* __restrict__ ws) {
  const int i = blockIdx.x;
  const int lvl = (i & 7) | ((i >> 13) << 3);
  const int chunk = (i >> 3) & 1023;
  const int b = chunk * 256 + threadIdx.x;
  const float px = __builtin_nontemporal_load(x + b * 3 + 0);
  const float py = __builtin_nontemporal_load(x + b * 3 + 1);
  const float pz = __builtin_nontemporal_load(x + b * 3 + 2);
  float o0, o1;
  ngp_point_level(px, py, pz, lvl, tables, o0, o1);
  vf2 r; r.x = o0; r.y = o1;
  __builtin_nontemporal_store(r, ws + (size_t)lvl * NB + b);
}

__global__ __launch_bounds__(256) void ngp_transpose_kernel(
    const vf2* __restrict__ ws, vf4* __restrict__ out4) {
  __shared__ vf2 tile[NL][257];
  const int t = threadIdx.x;
  const int p0 = blockIdx.x * 256;
#pragma unroll
  for (int l = 0; l < NL; ++l) {
    tile[l][t] = __builtin_nontemporal_load(ws + (size_t)l * NB + p0 + t);
  }
  __syncthreads();
#pragma unroll
  for (int k = 0; k < 8; ++k) {
    const int q = k * 256 + t;
    const int pq = q >> 3;
    const int wq = q & 7;
    const vf2 a = tile[2 * wq + 0][pq];
    const vf2 c = tile[2 * wq + 1][pq];
    vf4 v; v.x = a.x; v.y = a.y; v.z = c.x; v.w = c.y;
    __builtin_nontemporal_store(v, out4 + (size_t)p0 * 8 + q);
  }
}

// ---- last-resort fused fallback ----
__global__ __launch_bounds__(256) void ngp_fused_kernel(
    const float* __restrict__ x, const float* __restrict__ tables,
    float* __restrict__ out) {
  const int tid = blockIdx.x * blockDim.x + threadIdx.x;
  const int l = tid & (NL - 1);
  const int b = tid >> 4;
  float o0, o1;
  ngp_point_level(x[b * 3], x[b * 3 + 1], x[b * 3 + 2], l, tables, o0, o1);
  float2 r = make_float2(o0, o1);
  ((float2*)out)[tid] = r;
}

extern "C" void kernel_launch(void* const* d_in, const int* in_sizes, int n_in,
                              void* d_out, int out_size, void* d_ws, size_t ws_size,
                              hipStream_t stream) {
  const float* x = (const float*)d_in[0];
  const float* tables = (const float*)d_in[1];
  float* out = (float*)d_out;

  const size_t ws2_b = (size_t)NL * NB * sizeof(vf2);     // 32 MB
  const size_t xp_b = (size_t)NB * sizeof(vf4);           // 4 MB
  const size_t hist_b = (size_t)NBKT * sizeof(unsigned);  // 128 KB
  const size_t sorted_need = ws2_b + xp_b + 2 * hist_b;

  if (ws_size >= sorted_need) {
    char* base = (char*)d_ws;
    vf2* ws2 = (vf2*)base;
    vf4* xp = (vf4*)(base + ws2_b);
    unsigned* hist = (unsigned*)(base + ws2_b + xp_b);
    unsigned* offs = (unsigned*)(base + ws2_b + xp_b + hist_b);

    zero_kernel<<<NBKT / 256, 256, 0, stream>>>(hist);
    hist_kernel<<<NB / 256, 256, 0, stream>>>(x, hist);
    scan_kernel<<<1, 1024, 0, stream>>>(hist, offs);
    scatter_kernel<<<NB / 256, 256, 0, stream>>>(x, offs, xp);
    ngp_gather_sorted_kernel<<<NB * NL / 256, 256, 0, stream>>>(xp, tables, ws2);
    ngp_transpose_sorted_kernel<<<NB / 256, 256, 0, stream>>>(ws2, xp, (vf4*)out);
  } else if (ws_size >= ws2_b) {
    vf2* ws = (vf2*)d_ws;
    ngp_gather_kernel<<<NB * NL / 256, 256, 0, stream>>>(x, tables, ws);
    ngp_transpose_kernel<<<NB / 256, 256, 0, stream>>>(ws, (vf4*)out);
  } else {
    ngp_fused_kernel<<<NB * NL / 256, 256, 0, stream>>>(x, tables, out);
  }
}